// Round 1
// baseline (1006.317 us; speedup 1.0000x reference)
//
#include <hip/hip_runtime.h>

#define DIM 128

// ---------------------------------------------------------------------------
// Kernel 1: scatter-add h[src] into sum[dst], count edges per dst.
// 2 edges per 256-thread block; thread handles one feature element.
// ---------------------------------------------------------------------------
__global__ void scatter_kernel(const float* __restrict__ h,
                               const int* __restrict__ src,
                               const int* __restrict__ dst,
                               float* __restrict__ sum,   // [N, D] (aliases d_out)
                               float* __restrict__ cnt,   // [N]
                               int E)
{
    const int tid = threadIdx.x;
    const int e = blockIdx.x * 2 + (tid >> 7);
    const int d = tid & 127;
    if (e >= E) return;
    const int s  = src[e];
    const int dd = dst[e];
    atomicAdd(&sum[(size_t)dd * DIM + d], h[(size_t)s * DIM + d]);
    if (d == 0) atomicAdd(&cnt[dd], 1.0f);
}

// ---------------------------------------------------------------------------
// Kernel 2: transpose W [j][d] -> Wt [d][j] (tiny: 16384 elements)
// ---------------------------------------------------------------------------
__global__ void transpose_kernel(const float* __restrict__ W,
                                 float* __restrict__ Wt)
{
    const int i = blockIdx.x * 256 + threadIdx.x;   // 0..16383
    const int j = i >> 7;
    const int d = i & 127;
    Wt[d * DIM + j] = W[i];
}

// ---------------------------------------------------------------------------
// Kernel 3: per node: agg = cnt>0 ? sum/cnt : h ; out = ReLU(agg @ W^T + b)
// One wave handles 8 nodes. Lane t computes output columns t and t+64.
// Reads sum rows from d_out, overwrites d_out in place (block-private rows).
// ---------------------------------------------------------------------------
__global__ __launch_bounds__(256) void update_kernel(
    const float* __restrict__ h,
    const float* __restrict__ cnt,
    const float* __restrict__ Wt,    // [d][j] transposed weights
    const float* __restrict__ bias,  // [D]
    float* __restrict__ out,         // in: sum rows, out: result
    int N)
{
    const int t = threadIdx.x & 63;
    const int w = threadIdx.x >> 6;
    const int nbase = blockIdx.x * 32 + w * 8;

    const float* rowp[8];
    float scale[8];
#pragma unroll
    for (int n = 0; n < 8; ++n) {
        int node = nbase + n;
        int cl = node < N ? node : N - 1;
        float c = cnt[cl];
        bool use_sum = (c > 0.0f);
        rowp[n] = (use_sum ? (const float*)out : h) + (size_t)cl * DIM;
        scale[n] = use_sum ? (1.0f / c) : 1.0f;
    }

    float acc0[8], acc1[8];
    const float b0 = bias[t];
    const float b1 = bias[t + 64];
#pragma unroll
    for (int n = 0; n < 8; ++n) { acc0[n] = b0; acc1[n] = b1; }

#pragma unroll 2
    for (int d = 0; d < DIM; ++d) {
        const float wt0 = Wt[d * DIM + t];
        const float wt1 = Wt[d * DIM + t + 64];
#pragma unroll
        for (int n = 0; n < 8; ++n) {
            const float a = rowp[n][d] * scale[n];
            acc0[n] = fmaf(a, wt0, acc0[n]);
            acc1[n] = fmaf(a, wt1, acc1[n]);
        }
    }

#pragma unroll
    for (int n = 0; n < 8; ++n) {
        int node = nbase + n;
        if (node < N) {
            out[(size_t)node * DIM + t]      = fmaxf(acc0[n], 0.0f);
            out[(size_t)node * DIM + t + 64] = fmaxf(acc1[n], 0.0f);
        }
    }
}

// ---------------------------------------------------------------------------
extern "C" void kernel_launch(void* const* d_in, const int* in_sizes, int n_in,
                              void* d_out, int out_size, void* d_ws, size_t ws_size,
                              hipStream_t stream)
{
    const float* h  = (const float*)d_in[0];
    const int* src  = (const int*)d_in[1];
    const int* dst  = (const int*)d_in[2];
    const float* W  = (const float*)d_in[3];
    const float* b  = (const float*)d_in[4];
    float* out = (float*)d_out;

    const int N = in_sizes[0] / DIM;
    const int E = in_sizes[1];

    // Workspace layout: [0, N*4) cnt ; [512KB, 512KB+64KB) Wt
    float* cnt = (float*)d_ws;
    float* Wt  = (float*)((char*)d_ws + (1 << 19));

    // Zero the sum buffer (d_out) and counts every call (deterministic).
    hipMemsetAsync(out, 0, (size_t)N * DIM * sizeof(float), stream);
    hipMemsetAsync(cnt, 0, (size_t)N * sizeof(float), stream);

    transpose_kernel<<<(DIM * DIM) / 256, 256, 0, stream>>>(W, Wt);
    scatter_kernel<<<(E + 1) / 2, 256, 0, stream>>>(h, src, dst, out, cnt, E);
    update_kernel<<<(N + 31) / 32, 256, 0, stream>>>(h, cnt, Wt, b, out, N);
}